// Round 1
// baseline (460.980 us; speedup 1.0000x reference)
//
#include <hip/hip_runtime.h>
#include <hip/hip_bf16.h>
#include <stdint.h>

#define N_VOX 131072
#define KVOL  27
#define PPK   65536
#define CIN   64
#define COUT  64

typedef __attribute__((ext_vector_type(8))) short short8;
typedef __attribute__((ext_vector_type(4))) float f32x4;

__device__ __forceinline__ void gl_lds16(const void* g, void* l) {
  __builtin_amdgcn_global_load_lds(
      (const __attribute__((address_space(1))) unsigned int*)g,
      (__attribute__((address_space(3))) unsigned int*)l,
      16, 0, 0);
}

__device__ __forceinline__ unsigned short f2bf(float f) {
  __hip_bfloat16 h = __float2bfloat16(f);
  return *reinterpret_cast<unsigned short*>(&h);
}

// in_feats fp32 -> bf16, 8 elems/thread
__global__ __launch_bounds__(256) void cast_in_kernel(const float* __restrict__ in,
                                                      unsigned short* __restrict__ out) {
  int i = blockIdx.x * blockDim.x + threadIdx.x;   // one short8 per thread
  const float4* in4 = (const float4*)in;
  float4 f0 = in4[2 * i], f1 = in4[2 * i + 1];
  union { unsigned short u[8]; short8 v; } r;
  r.u[0] = f2bf(f0.x); r.u[1] = f2bf(f0.y); r.u[2] = f2bf(f0.z); r.u[3] = f2bf(f0.w);
  r.u[4] = f2bf(f1.x); r.u[5] = f2bf(f1.y); r.u[6] = f2bf(f1.z); r.u[7] = f2bf(f1.w);
  ((short8*)out)[i] = r.v;
}

// kernel [27][CIN][COUT] fp32 -> Wt [27][COUT][CIN] bf16
__global__ __launch_bounds__(256) void wt_kernel(const float* __restrict__ w,
                                                 unsigned short* __restrict__ wt) {
  int k = blockIdx.x;
  const float* wk = w + k * CIN * COUT;
  unsigned short* wtk = wt + k * CIN * COUT;
  for (int idx = threadIdx.x; idx < CIN * COUT; idx += 256) {
    int c = idx >> 6, o = idx & 63;
    wtk[o * 64 + c] = f2bf(wk[idx]);
  }
}

// out[n][c] = bias[c]
__global__ __launch_bounds__(256) void init_out_kernel(float* __restrict__ out,
                                                       const float* __restrict__ bias) {
  int i = blockIdx.x * blockDim.x + threadIdx.x;   // one float4 per thread
  float4 b = *(const float4*)(bias + ((i * 4) & 63));
  ((float4*)out)[i] = b;
}

// Fused gather -> bf16 MFMA -> atomic scatter.
// grid = 27*512 blocks; block handles offset k = bid>>9, pairs [pb*128, pb*128+128)
__global__ __launch_bounds__(256) void spconv_kernel(
    const unsigned short* __restrict__ inb,   // [N][64] bf16
    const unsigned short* __restrict__ wt,    // [27][COUT][CIN] bf16
    const int* __restrict__ imap, const int* __restrict__ omap,
    float* __restrict__ out) {
  // fragment-major chunk layout: chunk(r,s,q,m) = r*128 + s*64 + q*16 + m, 16B each
  __shared__ __align__(16) short A_lds[128 * 64];  // 16 KB: 128 pairs x 64 cin
  __shared__ __align__(16) short B_lds[64 * 64];   //  8 KB: 64 cout x 64 cin

  int bid = blockIdx.x;
  int k = bid >> 9;
  int pbase = (bid & 511) * 128;
  int tid = threadIdx.x;
  int wave = tid >> 6, lane = tid & 63;
  int m = lane & 15, q = lane >> 4;

  const int* imk = imap + k * PPK;
  const int* omk = omap + k * PPK;
  const unsigned short* wtk = wt + k * 4096;

  // Stage B (Wt[k]): 8 wave-instructions; id = wave*2 + i -> (t = id>>1, s = id&1)
#pragma unroll
  for (int i = 0; i < 2; i++) {
    int id = wave * 2 + i;
    int t = id >> 1, s = id & 1;
    const unsigned short* g = wtk + (t * 16 + m) * 64 + s * 32 + q * 8;
    gl_lds16(g, &B_lds[(t * 128 + s * 64) * 8]);
  }
  // Stage A (gathered rows): wave handles row-blocks r = wave*2 + j
#pragma unroll
  for (int j = 0; j < 2; j++) {
    int r = wave * 2 + j;
    int row = imk[pbase + r * 16 + m];
    const unsigned short* g0 = inb + row * 64 + q * 8;
    gl_lds16(g0,      &A_lds[(r * 128)      * 8]);   // s=0: k 0..31
    gl_lds16(g0 + 32, &A_lds[(r * 128 + 64) * 8]);   // s=1: k 32..63
  }
  __syncthreads();

  const short8* Af = (const short8*)A_lds;
  const short8* Bf = (const short8*)B_lds;

  short8 a[2][2], b[4][2];
#pragma unroll
  for (int r2 = 0; r2 < 2; r2++) {
    int r = wave * 2 + r2;
#pragma unroll
    for (int s = 0; s < 2; s++) a[r2][s] = Af[r * 128 + s * 64 + lane];
  }
#pragma unroll
  for (int t = 0; t < 4; t++)
#pragma unroll
    for (int s = 0; s < 2; s++) b[t][s] = Bf[t * 128 + s * 64 + lane];

  f32x4 acc[2][4];
#pragma unroll
  for (int r2 = 0; r2 < 2; r2++)
#pragma unroll
    for (int t = 0; t < 4; t++) {
      f32x4 c = {0.f, 0.f, 0.f, 0.f};
      c = __builtin_amdgcn_mfma_f32_16x16x32_bf16(a[r2][0], b[t][0], c, 0, 0, 0);
      c = __builtin_amdgcn_mfma_f32_16x16x32_bf16(a[r2][1], b[t][1], c, 0, 0, 0);
      acc[r2][t] = c;
    }

  // Epilogue: C layout col = lane&15 (=m), row = q*4 + reg
  int orow[2][4];
#pragma unroll
  for (int r2 = 0; r2 < 2; r2++) {
    int pr = pbase + (wave * 2 + r2) * 16 + q * 4;
#pragma unroll
    for (int reg = 0; reg < 4; reg++) orow[r2][reg] = omk[pr + reg];
  }
#pragma unroll
  for (int r2 = 0; r2 < 2; r2++)
#pragma unroll
    for (int t = 0; t < 4; t++)
#pragma unroll
      for (int reg = 0; reg < 4; reg++)
        atomicAdd(out + (size_t)orow[r2][reg] * 64 + t * 16 + m, acc[r2][t][reg]);
}

extern "C" void kernel_launch(void* const* d_in, const int* in_sizes, int n_in,
                              void* d_out, int out_size, void* d_ws, size_t ws_size,
                              hipStream_t stream) {
  const float* in_feats = (const float*)d_in[0];
  const float* kern     = (const float*)d_in[1];
  const float* bias     = (const float*)d_in[2];
  const int*   imap     = (const int*)d_in[3];
  const int*   omap     = (const int*)d_in[4];
  float* out = (float*)d_out;

  unsigned short* inb = (unsigned short*)d_ws;                 // 131072*64 bf16 = 16 MB
  unsigned short* wt  = inb + (size_t)N_VOX * CIN;             // 27*4096 bf16

  cast_in_kernel<<<(N_VOX * CIN / 8) / 256, 256, 0, stream>>>(in_feats, inb);
  wt_kernel<<<KVOL, 256, 0, stream>>>(kern, wt);
  init_out_kernel<<<(N_VOX * COUT / 4) / 256, 256, 0, stream>>>(out, bias);
  spconv_kernel<<<KVOL * (PPK / 128), 256, 0, stream>>>(inb, wt, imap, omap, out);
}